// Round 7
// baseline (97.345 us; speedup 1.0000x reference)
//
#include <hip/hip_runtime.h>

#define BQ 32
#define TQ 128
#define U1Q 65
#define UMAXQ 64
#define DQ 512
#define SLAB (TQ * U1Q)          // 8320 floats per array per batch
#define NEGQ (-1e30f)
#define L2E 1.4426950408889634f
#define LN2F 0.6931471805599453f

typedef float f4 __attribute__((ext_vector_type(4)));

// log2-domain logaddexp: log2(2^x + 2^y). exp2f/log2f are native on CDNA.
__device__ __forceinline__ float logadd2(float x, float y) {
    float mx = fmaxf(x, y);
    float d  = fminf(x, y) - mx;            // <= 0; exp2 underflows cleanly
    return mx + log2f(1.0f + exp2f(d));
}

// Kernel 0: per-batch alive-row counts -> exclusive prefix table offt[0..32].
__global__ __launch_bounds__(64) void prep_k(const int* __restrict__ llen,
                                             const int* __restrict__ tlen,
                                             int* __restrict__ offt) {
    int lane = threadIdx.x;
    int v = (lane < BQ) ? llen[lane] * (tlen[lane] + 1) : 0;
    int p = v;
#pragma unroll
    for (int d = 1; d <= 16; d <<= 1) { int o = __shfl_up(p, d, 64); if (lane >= d) p += o; }
    if (lane < BQ) offt[lane + 1] = p;
    if (lane == 0) offt[0] = 0;
}

// Phase 1: persistent grid-stride over COMPACTED alive rows. 4 rows/wave,
// 16 lanes/row, nontemporal streaming loads; no dead waves, balanced.
// ws layout: per batch b, ws[b*2*SLAB + q]=lp_blank, ws[b*2*SLAB+SLAB+q]=lp_emit
// (q = t*U1Q+u), both log2-domain.
__global__ __launch_bounds__(512) void lse_k(const float* __restrict__ logits,
                                             const int* __restrict__ targets,
                                             const int* __restrict__ tlen,
                                             const int* __restrict__ offt,
                                             float* __restrict__ ws) {
    __shared__ int Soff[BQ + 1];
    __shared__ int Stl[BQ];
    int tid = threadIdx.x;
    if (tid < BQ + 1) Soff[tid] = offt[tid];
    if (tid < BQ)     Stl[tid]  = tlen[tid];
    __syncthreads();
    int total = Soff[BQ];

    int lane = tid & 63;
    int g = lane >> 4;          // row slot within wave
    int i = lane & 15;          // sublane within row
    int wid = blockIdx.x * 8 + (tid >> 6);
    int stride = gridDim.x * 8 * 4;

    for (int base = wid * 4; base < total; base += stride) {
        int ar = base + g;
        bool alive = (ar < total);
        if (!alive) ar = total - 1;          // clamp; writes masked by 'alive'

        // locate batch: offt[b] <= ar < offt[b+1]
        int lo = 0, hi = BQ;
#pragma unroll
        for (int it = 0; it < 5; ++it) { int mid = (lo + hi) >> 1; if (ar >= Soff[mid]) lo = mid; else hi = mid; }
        int b = lo;
        int tl = Stl[b];
        int P = tl + 1;
        int local = ar - Soff[b];
        int t = local / P;
        int u = local - t * P;
        int q = t * U1Q + u;

        const f4* rp = (const f4*)(logits + ((size_t)b * SLAB + q) * DQ) + i;
        f4 v0 = __builtin_nontemporal_load(rp);
        f4 v1 = __builtin_nontemporal_load(rp + 16);
        f4 v2 = __builtin_nontemporal_load(rp + 32);
        f4 v3 = __builtin_nontemporal_load(rp + 48);
        f4 v4 = __builtin_nontemporal_load(rp + 64);
        f4 v5 = __builtin_nontemporal_load(rp + 80);
        f4 v6 = __builtin_nontemporal_load(rp + 96);
        f4 v7 = __builtin_nontemporal_load(rp + 112);

#define MAX4(v) fmaxf(fmaxf((v).x, (v).y), fmaxf((v).z, (v).w))
        float m = fmaxf(fmaxf(fmaxf(MAX4(v0), MAX4(v1)), fmaxf(MAX4(v2), MAX4(v3))),
                        fmaxf(fmaxf(MAX4(v4), MAX4(v5)), fmaxf(MAX4(v6), MAX4(v7))));
#pragma unroll
        for (int d = 1; d <= 8; d <<= 1) m = fmaxf(m, __shfl_xor(m, d, 64));

        float ml = m * L2E;
#define SUM4(v) (exp2f(fmaf((v).x, L2E, -ml)) + exp2f(fmaf((v).y, L2E, -ml)) + \
                 exp2f(fmaf((v).z, L2E, -ml)) + exp2f(fmaf((v).w, L2E, -ml)))
        float s = ((SUM4(v0) + SUM4(v1)) + (SUM4(v2) + SUM4(v3))) +
                  ((SUM4(v4) + SUM4(v5)) + (SUM4(v6) + SUM4(v7)));
#pragma unroll
        for (int d = 1; d <= 8; d <<= 1) s += __shfl_xor(s, d, 64);

        float l2s = log2f(s);
        float* wb = ws + (size_t)b * 2 * SLAB;

        // blank = element 511 = lane i==15's v7.w
        if (alive && i == 15) wb[q] = fmaf(v7.w, L2E, -ml) - l2s;

        int tgt = targets[b * UMAXQ + (u < UMAXQ ? u : UMAXQ - 1)];
        int itgt = (tgt >> 2) & 15;
        if (alive && i == itgt) {
            int ktgt = tgt >> 6, jt = tgt & 3;
            f4 c = v0;
            if (ktgt == 1) c = v1;
            if (ktgt == 2) c = v2;
            if (ktgt == 3) c = v3;
            if (ktgt == 4) c = v4;
            if (ktgt == 5) c = v5;
            if (ktgt == 6) c = v6;
            if (ktgt == 7) c = v7;
            float val = (jt == 0) ? c.x : ((jt == 1) ? c.y : ((jt == 2) ? c.z : c.w));
            wb[SLAB + q] = (u < tl) ? (fmaf(val, L2E, -ml) - l2s) : NEGQ;
        }
    }
}

// Phase 2: per batch, stage rows t<=tf of both slabs into LDS (8 waves), then
// wave 0 runs the anti-diagonal wavefront DP out of LDS (4-deep prefetch).
__global__ __launch_bounds__(512) void dp_k(const float* __restrict__ ws,
                                            const int* __restrict__ llen,
                                            const int* __restrict__ tlen,
                                            float* __restrict__ out) {
    __shared__ float S[2 * SLAB];
    int b   = blockIdx.x;
    int tid = threadIdx.x;

    int tf = llen[b] - 1;
    int uf = tlen[b];

    const f4* srcB = (const f4*)(ws + (size_t)b * 2 * SLAB);
    const f4* srcE = srcB + SLAB / 4;
    f4* dstB = (f4*)S;
    f4* dstE = (f4*)(S + SLAB);
    int nb4 = ((tf + 1) * U1Q + 3) >> 2;      // f4s covering rows 0..tf
    for (int idx = tid; idx < nb4; idx += 512) {
        dstB[idx] = srcB[idx];
        dstE[idx] = srcE[idx];
    }
    __syncthreads();
    if (tid >= 64) return;

    int lane = tid;
    const float* SB = S;
    const float* SE = S + SLAB;

    int kmax = tf + uf;

    float a   = (lane == 0) ? 0.0f : NEGQ;
    float a64 = NEGQ;
    int um1 = (lane > 0) ? lane - 1 : 0;

    // clamped (always in-bounds) diagonal reads from LDS; garbage is masked
    // or confined to lanes/diagonals that never reach the output.
    auto LB = [&](int k) { int t = k - lane - 1; t = t < 0 ? 0 : (t > TQ - 1 ? TQ - 1 : t);
                           return SB[t * U1Q + lane]; };
    auto LE = [&](int k) { int t = k - lane;     t = t < 0 ? 0 : (t > TQ - 1 ? TQ - 1 : t);
                           return SE[t * U1Q + um1]; };
    auto LB6 = [&](int k) { int t = k - 65; t = t < 0 ? 0 : (t > TQ - 1 ? TQ - 1 : t);
                            return SB[t * U1Q + 64]; };
    auto LE6 = [&](int k) { int t = k - 64; t = t < 0 ? 0 : (t > TQ - 1 ? TQ - 1 : t);
                            return SE[t * U1Q + 63]; };

#define STEP(kk, lbv, lev, lb6v, le6v) do {                                  \
    int k_ = (kk); int t = k_ - lane;                                        \
    float A   = (t >= 1) ? (a + (lbv)) : NEGQ;                               \
    float ash = __shfl_up(a, 1, 64);                                         \
    float Bv  = (lane >= 1 && t >= 0) ? (ash + (lev)) : NEGQ;                \
    float a63 = __shfl(a, 63, 64);                                           \
    float anew = logadd2(A, Bv);                                             \
    int t64 = k_ - 64;                                                       \
    float A64 = (t64 >= 1) ? (a64 + (lb6v)) : NEGQ;                          \
    float B64 = (t64 >= 0) ? (a63 + (le6v)) : NEGQ;                          \
    a64 = (t64 >= 0) ? logadd2(A64, B64) : NEGQ;                             \
    a = anew;                                                                \
} while (0)

    // 4-deep software-pipelined prefetch (all addresses clamped in-bounds)
    float lbA = LB(1), leA = LE(1), lb6A = LB6(1), le6A = LE6(1);
    float lbB = LB(2), leB = LE(2), lb6B = LB6(2), le6B = LE6(2);
    float lbC = LB(3), leC = LE(3), lb6C = LB6(3), le6C = LE6(3);
    float lbD = LB(4), leD = LE(4), lb6D = LB6(4), le6D = LE6(4);

    int k = 1;
    for (; k + 3 <= kmax; k += 4) {
        STEP(k,     lbA, leA, lb6A, le6A); lbA = LB(k + 4); leA = LE(k + 4); lb6A = LB6(k + 4); le6A = LE6(k + 4);
        STEP(k + 1, lbB, leB, lb6B, le6B); lbB = LB(k + 5); leB = LE(k + 5); lb6B = LB6(k + 5); le6B = LE6(k + 5);
        STEP(k + 2, lbC, leC, lb6C, le6C); lbC = LB(k + 6); leC = LE(k + 6); lb6C = LB6(k + 6); le6C = LE6(k + 6);
        STEP(k + 3, lbD, leD, lb6D, le6D); lbD = LB(k + 7); leD = LE(k + 7); lb6D = LB6(k + 7); le6D = LE6(k + 7);
    }
    if (k <= kmax) { STEP(k, lbA, leA, lb6A, le6A); k++; }
    if (k <= kmax) { STEP(k, lbB, leB, lb6B, le6B); k++; }
    if (k <= kmax) { STEP(k, lbC, leC, lb6C, le6C); k++; }

    float alpha_f = (uf >= 64) ? a64 : __shfl(a, uf, 64);
    if (lane == 0) out[b] = -(alpha_f + SB[tf * U1Q + uf]) * LN2F;
}

extern "C" void kernel_launch(void* const* d_in, const int* in_sizes, int n_in,
                              void* d_out, int out_size, void* d_ws, size_t ws_size,
                              hipStream_t stream) {
    const float* logits  = (const float*)d_in[0];
    const int*   llen    = (const int*)d_in[1];
    const int*   tlen    = (const int*)d_in[2];
    const int*   targets = (const int*)d_in[3];
    float*       out     = (float*)d_out;
    float*       ws      = (float*)d_ws;
    int*         offt    = (int*)(ws + (size_t)2 * SLAB * BQ);

    prep_k<<<1, 64, 0, stream>>>(llen, tlen, offt);
    // 1024 blocks x 512 thr = 4 blocks/CU resident; grid-stride over alive rows
    lse_k<<<1024, 512, 0, stream>>>(logits, targets, tlen, offt, ws);
    dp_k<<<BQ, 512, 0, stream>>>(ws, llen, tlen, out);
}

// Round 8
// 81.075 us; speedup vs baseline: 1.2007x; 1.2007x over previous
//
#include <hip/hip_runtime.h>

#define BQ 32
#define TQ 128
#define U1Q 65
#define UMAXQ 64
#define DQ 512
#define SLAB (TQ * U1Q)          // 8320 floats per array per batch
#define NCELLS (BQ * SLAB)
#define NEGQ (-1e30f)
#define L2E 1.4426950408889634f
#define LN2F 0.6931471805599453f

typedef float f4 __attribute__((ext_vector_type(4)));

#define EXP2(x) __builtin_amdgcn_exp2f(x)   // native v_exp_f32
#define LOG2(x) __builtin_amdgcn_logf(x)    // native v_log_f32 (log2)

// log2-domain logaddexp: log2(2^x + 2^y), native transcendentals.
__device__ __forceinline__ float logadd2(float x, float y) {
    float mx = fmaxf(x, y);
    float d  = fminf(x, y) - mx;            // <= 0; exp2 underflows cleanly
    return mx + LOG2(1.0f + EXP2(d));
}

// Phase 1: 4 rows per wave, 16 lanes per row; nontemporal streaming loads.
// Rows with t >= llen[b] or u > tlen[b] are never consumed by the DP -> skip
// them before loading (cuts HBM read to ~57%).
// ws layout: per batch b, ws[b*2*SLAB + q] = lp_blank, ws[b*2*SLAB + SLAB + q]
// = lp_emit (q = t*U1Q + u), both log2-domain.
__global__ __launch_bounds__(512) void lse_k(const float* __restrict__ logits,
                                             const int* __restrict__ targets,
                                             const int* __restrict__ llen,
                                             const int* __restrict__ tlen,
                                             float* __restrict__ ws) {
    int wid  = (blockIdx.x * 512 + threadIdx.x) >> 6;
    int lane = threadIdx.x & 63;
    int g = lane >> 4;          // row within wave
    int i = lane & 15;          // sublane within row
    int r = wid * 4 + g;        // global cell index (grid sized exactly)

    int b = r / SLAB;
    int q = r - b * SLAB;
    int t = q / U1Q;
    int u = q - t * U1Q;
    int tl = tlen[b];
    if (t >= llen[b] || u > tl) return;   // uniform across the 16-lane group

    const f4* rp = (const f4*)(logits + (size_t)r * DQ) + i;
    // lane i holds elements {4i + 64k + j : k=0..7, j=0..3}
    f4 v0 = __builtin_nontemporal_load(rp);
    f4 v1 = __builtin_nontemporal_load(rp + 16);
    f4 v2 = __builtin_nontemporal_load(rp + 32);
    f4 v3 = __builtin_nontemporal_load(rp + 48);
    f4 v4 = __builtin_nontemporal_load(rp + 64);
    f4 v5 = __builtin_nontemporal_load(rp + 80);
    f4 v6 = __builtin_nontemporal_load(rp + 96);
    f4 v7 = __builtin_nontemporal_load(rp + 112);

#define MAX4(v) fmaxf(fmaxf((v).x, (v).y), fmaxf((v).z, (v).w))
    float m = fmaxf(fmaxf(fmaxf(MAX4(v0), MAX4(v1)), fmaxf(MAX4(v2), MAX4(v3))),
                    fmaxf(fmaxf(MAX4(v4), MAX4(v5)), fmaxf(MAX4(v6), MAX4(v7))));
#pragma unroll
    for (int d = 1; d <= 8; d <<= 1) m = fmaxf(m, __shfl_xor(m, d, 64));

    float ml = m * L2E;
#define SUM4(v) (EXP2(fmaf((v).x, L2E, -ml)) + EXP2(fmaf((v).y, L2E, -ml)) + \
                 EXP2(fmaf((v).z, L2E, -ml)) + EXP2(fmaf((v).w, L2E, -ml)))
    float s = ((SUM4(v0) + SUM4(v1)) + (SUM4(v2) + SUM4(v3))) +
              ((SUM4(v4) + SUM4(v5)) + (SUM4(v6) + SUM4(v7)));
#pragma unroll
    for (int d = 1; d <= 8; d <<= 1) s += __shfl_xor(s, d, 64);

    float l2s = LOG2(s);
    float* wb = ws + (size_t)b * 2 * SLAB;

    // blank = element 511 = lane i==15's v7.w
    if (i == 15) wb[q] = fmaf(v7.w, L2E, -ml) - l2s;

    int tgt = targets[b * UMAXQ + (u < UMAXQ ? u : UMAXQ - 1)];
    int itgt = (tgt >> 2) & 15;
    if (i == itgt) {
        int ktgt = tgt >> 6, jt = tgt & 3;
        f4 c = v0;
        if (ktgt == 1) c = v1;
        if (ktgt == 2) c = v2;
        if (ktgt == 3) c = v3;
        if (ktgt == 4) c = v4;
        if (ktgt == 5) c = v5;
        if (ktgt == 6) c = v6;
        if (ktgt == 7) c = v7;
        float val = (jt == 0) ? c.x : ((jt == 1) ? c.y : ((jt == 2) ? c.z : c.w));
        wb[SLAB + q] = (u < tl) ? (fmaf(val, L2E, -ml) - l2s) : NEGQ;
    }
}

// Phase 2: per batch, stage rows t<=tf of both slabs into LDS (8 waves), then
// wave 0 runs the anti-diagonal wavefront DP out of LDS (4-deep prefetch).
__global__ __launch_bounds__(512) void dp_k(const float* __restrict__ ws,
                                            const int* __restrict__ llen,
                                            const int* __restrict__ tlen,
                                            float* __restrict__ out) {
    __shared__ float S[2 * SLAB];
    int b   = blockIdx.x;
    int tid = threadIdx.x;

    int tf = llen[b] - 1;
    int uf = tlen[b];

    const f4* srcB = (const f4*)(ws + (size_t)b * 2 * SLAB);
    const f4* srcE = srcB + SLAB / 4;
    f4* dstB = (f4*)S;
    f4* dstE = (f4*)(S + SLAB);
    int nb4 = ((tf + 1) * U1Q + 3) >> 2;      // f4s covering rows 0..tf
    for (int idx = tid; idx < nb4; idx += 512) {
        dstB[idx] = srcB[idx];
        dstE[idx] = srcE[idx];
    }
    __syncthreads();
    if (tid >= 64) return;

    int lane = tid;
    const float* SB = S;
    const float* SE = S + SLAB;

    int kmax = tf + uf;

    float a   = (lane == 0) ? 0.0f : NEGQ;
    float a64 = NEGQ;
    int um1 = (lane > 0) ? lane - 1 : 0;

    // clamped (always in-bounds) diagonal reads from LDS; garbage is masked
    // or confined to lanes/diagonals that never reach the output.
    auto LB = [&](int k) { int t = k - lane - 1; t = t < 0 ? 0 : (t > TQ - 1 ? TQ - 1 : t);
                           return SB[t * U1Q + lane]; };
    auto LE = [&](int k) { int t = k - lane;     t = t < 0 ? 0 : (t > TQ - 1 ? TQ - 1 : t);
                           return SE[t * U1Q + um1]; };
    auto LB6 = [&](int k) { int t = k - 65; t = t < 0 ? 0 : (t > TQ - 1 ? TQ - 1 : t);
                            return SB[t * U1Q + 64]; };
    auto LE6 = [&](int k) { int t = k - 64; t = t < 0 ? 0 : (t > TQ - 1 ? TQ - 1 : t);
                            return SE[t * U1Q + 63]; };

#define STEP(kk, lbv, lev, lb6v, le6v) do {                                  \
    int k_ = (kk); int t = k_ - lane;                                        \
    float A   = (t >= 1) ? (a + (lbv)) : NEGQ;                               \
    float ash = __shfl_up(a, 1, 64);                                         \
    float Bv  = (lane >= 1 && t >= 0) ? (ash + (lev)) : NEGQ;                \
    float a63 = __shfl(a, 63, 64);                                           \
    float anew = logadd2(A, Bv);                                             \
    int t64 = k_ - 64;                                                       \
    float A64 = (t64 >= 1) ? (a64 + (lb6v)) : NEGQ;                          \
    float B64 = (t64 >= 0) ? (a63 + (le6v)) : NEGQ;                          \
    a64 = (t64 >= 0) ? logadd2(A64, B64) : NEGQ;                             \
    a = anew;                                                                \
} while (0)

    // 4-deep software-pipelined prefetch (all addresses clamped in-bounds)
    float lbA = LB(1), leA = LE(1), lb6A = LB6(1), le6A = LE6(1);
    float lbB = LB(2), leB = LE(2), lb6B = LB6(2), le6B = LE6(2);
    float lbC = LB(3), leC = LE(3), lb6C = LB6(3), le6C = LE6(3);
    float lbD = LB(4), leD = LE(4), lb6D = LB6(4), le6D = LE6(4);

    int k = 1;
    for (; k + 3 <= kmax; k += 4) {
        STEP(k,     lbA, leA, lb6A, le6A); lbA = LB(k + 4); leA = LE(k + 4); lb6A = LB6(k + 4); le6A = LE6(k + 4);
        STEP(k + 1, lbB, leB, lb6B, le6B); lbB = LB(k + 5); leB = LE(k + 5); lb6B = LB6(k + 5); le6B = LE6(k + 5);
        STEP(k + 2, lbC, leC, lb6C, le6C); lbC = LB(k + 6); leC = LE(k + 6); lb6C = LB6(k + 6); le6C = LE6(k + 6);
        STEP(k + 3, lbD, leD, lb6D, le6D); lbD = LB(k + 7); leD = LE(k + 7); lb6D = LB6(k + 7); le6D = LE6(k + 7);
    }
    if (k <= kmax) { STEP(k, lbA, leA, lb6A, le6A); k++; }
    if (k <= kmax) { STEP(k, lbB, leB, lb6B, le6B); k++; }
    if (k <= kmax) { STEP(k, lbC, leC, lb6C, le6C); k++; }

    float alpha_f = (uf >= 64) ? a64 : __shfl(a, uf, 64);
    if (lane == 0) out[b] = -(alpha_f + SB[tf * U1Q + uf]) * LN2F;
}

extern "C" void kernel_launch(void* const* d_in, const int* in_sizes, int n_in,
                              void* d_out, int out_size, void* d_ws, size_t ws_size,
                              hipStream_t stream) {
    const float* logits  = (const float*)d_in[0];
    const int*   llen    = (const int*)d_in[1];
    const int*   tlen    = (const int*)d_in[2];
    const int*   targets = (const int*)d_in[3];
    float*       out     = (float*)d_out;
    float*       ws      = (float*)d_ws;

    int blocks = NCELLS / 32;   // 8 waves/block x 4 rows/wave = 32 rows/block, exact
    lse_k<<<blocks, 512, 0, stream>>>(logits, targets, llen, tlen, ws);
    dp_k<<<BQ, 512, 0, stream>>>(ws, llen, tlen, out);
}